// Round 1
// baseline (1193.731 us; speedup 1.0000x reference)
//
#include <hip/hip_runtime.h>
#include <cstddef>

// Problem constants
constexpr int BATCH = 128;
constexpr int T     = 16;       // coarse grid
constexpr int ROWS  = BATCH * T * T;  // 32768
constexpr int WID   = 100;      // network width
constexpr int NB    = 50;       // residual blocks
constexpr int WJ    = 128;      // padded j extent (col dim of weight tiles)
constexpr int XR    = 68;       // row stride of xsT/vsT (64 rows + 4 pad)
constexpr int RPW   = 64;       // rows per workgroup in chain kernel

// ---------------------------------------------------------------------------
// Prep: pad weights [50][100][100] -> [50][100][128] (zero pad cols) and
// compute per-block column sums of Wa (for folding scalar bias b1).
// ---------------------------------------------------------------------------
__global__ __launch_bounds__(256) void prep_kernel(
    const float* __restrict__ Wa, const float* __restrict__ Wb,
    float* __restrict__ wpadA, float* __restrict__ wpadB,
    float* __restrict__ csA) {
  const int bid = blockIdx.x;          // 0..99
  const int bk  = bid % NB;
  const bool isA = bid < NB;
  const float* src = (isA ? Wa : Wb) + (size_t)bk * (WID * WID);
  float* dst = (isA ? wpadA : wpadB) + (size_t)bk * (WID * WJ);
  for (int i = threadIdx.x; i < WID * WJ; i += 256) {
    int k = i >> 7;          // / 128
    int j = i & (WJ - 1);
    dst[i] = (j < WID) ? src[k * WID + j] : 0.0f;
  }
  if (isA) {
    for (int j = threadIdx.x; j < WJ; j += 256) {
      float s = 0.0f;
      if (j < WID) {
        for (int k = 0; k < WID; ++k) s += src[k * WID + j];
      }
      csA[bk * WJ + j] = s;
    }
  }
}

// ---------------------------------------------------------------------------
// First layer: gather 45-wide stencil rows, x0 = relu(flat @ W0)
// 512 blocks x 256 threads; 64 rows/block, 4 threads per row (25 cols each).
// ---------------------------------------------------------------------------
__global__ __launch_bounds__(256) void first_layer_kernel(
    const float* __restrict__ inp, const float* __restrict__ W0,
    float* __restrict__ x0) {
  __shared__ float w0s[45 * WID];
  for (int i = threadIdx.x; i < 45 * WID; i += 256) w0s[i] = W0[i];
  __syncthreads();

  const int rq  = threadIdx.x >> 2;   // 0..63
  const int cq  = threadIdx.x & 3;    // 0..3
  const int row = blockIdx.x * 64 + rq;
  const int b   = row >> 8;
  const int t1  = (row >> 4) & 15;
  const int t2  = row & 15;
  const int g1  = 2 * t1, g2 = 2 * t2;
  const int g1m = (g1 + 31) & 31, g2m = (g2 + 31) & 31;
  const float* base = inp + (size_t)b * (32 * 32 * 9);
  const float* p0 = base + ((g1 + 1) * 32 + g2) * 9;    // right  (odd, even)
  const float* p1 = base + (g1m * 32 + g2) * 9;         // left   (idx, even)
  const float* p2 = base + (g1 * 32 + (g2 + 1)) * 9;    // up     (even, odd)
  const float* p3 = base + (g1 * 32 + g2m) * 9;         // down   (even, idx)
  const float* p4 = base + (g1 * 32 + g2) * 9;          // center (even, even)

  float f[45];
#pragma unroll
  for (int q = 0; q < 9; ++q) {
    f[q]      = p0[q];
    f[9 + q]  = p1[q];
    f[18 + q] = p2[q];
    f[27 + q] = p3[q];
    f[36 + q] = p4[q];
  }

  float acc[25];
#pragma unroll
  for (int j = 0; j < 25; ++j) acc[j] = 0.0f;
  const int j0 = cq * 25;
#pragma unroll
  for (int k = 0; k < 45; ++k) {    // full unroll: f[k] must stay in registers
    const float fv = f[k];
#pragma unroll
    for (int j = 0; j < 25; ++j) acc[j] += fv * w0s[k * WID + j0 + j];
  }
  float* orow = x0 + (size_t)row * WID + j0;
#pragma unroll
  for (int j = 0; j < 25; ++j) orow[j] = fmaxf(acc[j], 0.0f);
}

// ---------------------------------------------------------------------------
// Chain: 50 residual blocks fused. 512 WGs x 256 threads, 64 rows/WG.
// LDS: xsT[100][68] (x, transposed k-major), vsT[100][68], wbuf[50][128].
// Thread tile: 8 rows x 4 cols. k-loops run over the real 100 only.
// ---------------------------------------------------------------------------
__global__ __launch_bounds__(256) void chain_kernel(
    float* __restrict__ x0,            // in/out (per-WG disjoint rows)
    const float* __restrict__ wpadA, const float* __restrict__ wpadB,
    const float* __restrict__ csA,
    const float* __restrict__ B1, const float* __restrict__ B2,
    const float* __restrict__ B3, const float* __restrict__ B4,
    const float* __restrict__ M) {
  __shared__ __align__(16) float xsT[WID * XR];
  __shared__ __align__(16) float vsT[WID * XR];
  __shared__ __align__(16) float wbuf[50 * WJ];

  const int tid   = threadIdx.x;
  const int rbase = blockIdx.x * RPW;

  // load x0 tile -> xsT (transposed)
  for (int i = tid; i < RPW * WID; i += 256) {
    int r = i / WID;
    int k = i - r * WID;
    xsT[k * XR + r] = x0[(size_t)(rbase + r) * WID + k];
  }

  const int rg = tid >> 5;     // 0..7
  const int cg = tid & 31;     // 0..31
  const int r0 = rg * 8;
  const int j0 = cg * 4;

  float acc[8][4];

  auto stage = [&](const float* src) {     // copy 50x128 floats -> wbuf
    for (int i = tid; i < (50 * WJ) / 4; i += 256) {
      *(float4*)&wbuf[i * 4] = *(const float4*)&src[i * 4];
    }
  };
  auto zero_acc = [&]() {
#pragma unroll
    for (int rr = 0; rr < 8; ++rr)
#pragma unroll
      for (int jj = 0; jj < 4; ++jj) acc[rr][jj] = 0.0f;
  };
  auto kloop = [&](const float* xT, int kbase) {
#pragma unroll 2
    for (int kk = 0; kk < 50; ++kk) {
      const float4 xa = *(const float4*)&xT[(kbase + kk) * XR + r0];
      const float4 xb = *(const float4*)&xT[(kbase + kk) * XR + r0 + 4];
      const float4 w  = *(const float4*)&wbuf[kk * WJ + j0];
      const float xv[8] = {xa.x, xa.y, xa.z, xa.w, xb.x, xb.y, xb.z, xb.w};
      const float wv[4] = {w.x, w.y, w.z, w.w};
#pragma unroll
      for (int rr = 0; rr < 8; ++rr)
#pragma unroll
        for (int jj = 0; jj < 4; ++jj) acc[rr][jj] += xv[rr] * wv[jj];
    }
  };

  for (int bk = 0; bk < NB; ++bk) {
    const float* wa = wpadA + (size_t)bk * (WID * WJ);
    const float* wb = wpadB + (size_t)bk * (WID * WJ);

    // ---------------- GEMM1: v = 2*relu(2*((x+b1)@Wa) + b2) + b3 ----------
    __syncthreads();                 // xsT ready, wbuf free
    stage(wa);                       // Wa rows 0..49
    __syncthreads();
    zero_acc();
    kloop(xsT, 0);
    __syncthreads();                 // wbuf free
    stage(wa + 50 * WJ);             // Wa rows 50..99
    __syncthreads();
    kloop(xsT, 50);

    {
      const float b1 = B1[bk], b2 = B2[bk], b3 = B3[bk];
      if (j0 < WID) {
        const float4 cs = *(const float4*)&csA[bk * WJ + j0];
        const float csv[4] = {cs.x, cs.y, cs.z, cs.w};
#pragma unroll
        for (int jj = 0; jj < 4; ++jj) {
          float vv[8];
#pragma unroll
          for (int rr = 0; rr < 8; ++rr) {
            const float t = 2.0f * (acc[rr][jj] + b1 * csv[jj]) + b2;
            vv[rr] = 2.0f * fmaxf(t, 0.0f) + b3;
          }
          *(float4*)&vsT[(j0 + jj) * XR + r0]     = make_float4(vv[0], vv[1], vv[2], vv[3]);
          *(float4*)&vsT[(j0 + jj) * XR + r0 + 4] = make_float4(vv[4], vv[5], vv[6], vv[7]);
        }
      }
    }

    // ---------------- GEMM2: x = relu(x + (v@Wb)*m + b4) -------------------
    __syncthreads();                 // vsT ready, wbuf free
    stage(wb);
    __syncthreads();
    zero_acc();
    kloop(vsT, 0);
    __syncthreads();
    stage(wb + 50 * WJ);
    __syncthreads();
    kloop(vsT, 50);

    {
      const float b4 = B4[bk], m = M[bk];
      if (j0 < WID) {
#pragma unroll
        for (int jj = 0; jj < 4; ++jj) {
          const float4 xo1 = *(const float4*)&xsT[(j0 + jj) * XR + r0];
          const float4 xo2 = *(const float4*)&xsT[(j0 + jj) * XR + r0 + 4];
          const float xo[8] = {xo1.x, xo1.y, xo1.z, xo1.w, xo2.x, xo2.y, xo2.z, xo2.w};
          float xn[8];
#pragma unroll
          for (int rr = 0; rr < 8; ++rr)
            xn[rr] = fmaxf(xo[rr] + acc[rr][jj] * m + b4, 0.0f);
          *(float4*)&xsT[(j0 + jj) * XR + r0]     = make_float4(xn[0], xn[1], xn[2], xn[3]);
          *(float4*)&xsT[(j0 + jj) * XR + r0 + 4] = make_float4(xn[4], xn[5], xn[6], xn[7]);
        }
      }
    }
  }

  __syncthreads();
  for (int i = tid; i < RPW * WID; i += 256) {
    int r = i / WID;
    int k = i - r * WID;
    x0[(size_t)(rbase + r) * WID + k] = xsT[k * XR + r];
  }
}

// ---------------------------------------------------------------------------
// Output head + stencil epilogue. One block per batch image (16x16 grid).
// ---------------------------------------------------------------------------
__global__ __launch_bounds__(256) void out_kernel(
    const float* __restrict__ inp, const float* __restrict__ x0,
    const float* __restrict__ Wout, const float* __restrict__ bout,
    float* __restrict__ out) {
  __shared__ float ys[256 * 4];
  __shared__ float wouts[WID * 4];
  __shared__ float bos[4];
  const int tid = threadIdx.x;
  const int b   = blockIdx.x;

  for (int i = tid; i < WID * 4; i += 256) wouts[i] = Wout[i];
  if (tid < 4) bos[tid] = bout[tid];
  __syncthreads();

  const int row = b * 256 + tid;
  const float* xr = x0 + (size_t)row * WID;
  float a0 = 0.f, a1 = 0.f, a2 = 0.f, a3 = 0.f;
#pragma unroll 4
  for (int k = 0; k < WID; ++k) {
    const float xv = xr[k];
    a0 += xv * wouts[k * 4 + 0];
    a1 += xv * wouts[k * 4 + 1];
    a2 += xv * wouts[k * 4 + 2];
    a3 += xv * wouts[k * 4 + 3];
  }
  ys[tid * 4 + 0] = a0 + bos[0];
  ys[tid * 4 + 1] = a1 + bos[1];
  ys[tid * 4 + 2] = a2 + bos[2];
  ys[tid * 4 + 3] = a3 + bos[3];
  __syncthreads();

  const int i = tid >> 4, j = tid & 15;
  const int ip1 = (i + 1) & 15, im1 = (i + 15) & 15;
  const int jp1 = (j + 1) & 15, jm1 = (j + 15) & 15;
  auto Y = [&](int a, int c, int comp) { return ys[(((a << 4) | c) << 2) + comp]; };
  const float y0 = Y(i, j, 0), y1 = Y(i, j, 1), y2 = Y(i, j, 2), y3 = Y(i, j, 3);
  const float right_c = y0 / (Y(ip1, j, 1) + y0);
  const float left_c  = y1 / (y1 + Y(im1, j, 0));
  const float up_c    = y2 / (y2 + Y(i, jp1, 3));
  const float down_c  = y3 / (Y(i, jm1, 2) + y3);

  const float* base = inp + (size_t)b * (32 * 32 * 9);
  const int g1 = 2 * i + 1, g1m = (2 * i + 31) & 31;
  const int g2 = 2 * j + 1, g2m = (2 * j + 31) & 31;
  const float* oo = base + (g1 * 32 + g2) * 9;    // odd, odd
  const float* oi = base + (g1 * 32 + g2m) * 9;   // odd, idx
  const float* io = base + (g1m * 32 + g2) * 9;   // idx, odd
  const float* ii = base + (g1m * 32 + g2m) * 9;  // idx, idx
  const float ru = -(oo[0] + oo[3] * right_c + oo[1] * up_c) / oo[4];
  const float rd = -(oi[2] + oi[5] * right_c + oi[1] * down_c) / oi[4];
  const float lu = -(io[6] + io[3] * left_c + io[7] * up_c) / io[4];
  const float ld = -(ii[8] + ii[5] * left_c + ii[7] * down_c) / ii[4];

  float* o = out + (size_t)row * 9;
  o[0] = ld;     o[1] = left_c;  o[2] = lu;
  o[3] = down_c; o[4] = 1.0f;    o[5] = up_c;
  o[6] = rd;     o[7] = right_c; o[8] = ru;
}

// ---------------------------------------------------------------------------
extern "C" void kernel_launch(void* const* d_in, const int* in_sizes, int n_in,
                              void* d_out, int out_size, void* d_ws, size_t ws_size,
                              hipStream_t stream) {
  const float* inp  = (const float*)d_in[0];
  const float* W0   = (const float*)d_in[1];
  const float* Wa   = (const float*)d_in[2];
  const float* Wb   = (const float*)d_in[3];
  const float* B1   = (const float*)d_in[4];
  const float* B2   = (const float*)d_in[5];
  const float* B3   = (const float*)d_in[6];
  const float* B4   = (const float*)d_in[7];
  const float* M    = (const float*)d_in[8];
  const float* Wout = (const float*)d_in[9];
  const float* bout = (const float*)d_in[10];
  float* out = (float*)d_out;

  float* ws    = (float*)d_ws;
  float* x0    = ws;                          // 32768*100       = 3,276,800 floats
  float* wpadA = ws + 3276800;                // 50*100*128      =   640,000
  float* wpadB = wpadA + 640000;              //                 =   640,000
  float* csA   = wpadB + 640000;              // 50*128          =     6,400

  hipLaunchKernelGGL(prep_kernel, dim3(100), dim3(256), 0, stream,
                     Wa, Wb, wpadA, wpadB, csA);
  hipLaunchKernelGGL(first_layer_kernel, dim3(ROWS / 64), dim3(256), 0, stream,
                     inp, W0, x0);
  hipLaunchKernelGGL(chain_kernel, dim3(ROWS / RPW), dim3(256), 0, stream,
                     x0, wpadA, wpadB, csA, B1, B2, B3, B4, M);
  hipLaunchKernelGGL(out_kernel, dim3(BATCH), dim3(256), 0, stream,
                     inp, x0, Wout, bout, out);
}